// Round 5
// baseline (477.816 us; speedup 1.0000x reference)
//
#include <hip/hip_runtime.h>

#define N_ATOMS 65536
#define AF      133     // atom feature dim
#define BT      147     // bond feature total dim
#define HID     256
#define NNB     6
#define NM      2048

#define KI   160        // atom(133) padded
#define KB   32         // bond(14) padded
#define KP   256        // proj GEMMs (exact)
// LDS strides (elements)
#define LSI  168
#define LSB  40
#define LSP  264
#define SE   264        // epilogue LDS stride (x2B = 528, 16B aligned, 4-way max on b16 writes)

typedef __attribute__((ext_vector_type(8))) short short8;
typedef __attribute__((ext_vector_type(4))) float f32x4;

__device__ __forceinline__ unsigned short f2bf(float f) {
    unsigned u = __builtin_bit_cast(unsigned, f);
    u += 0x7fffu + ((u >> 16) & 1u);     // round-to-nearest-even
    return (unsigned short)(u >> 16);
}
__device__ __forceinline__ float bf2f(unsigned short s) {
    unsigned u = ((unsigned)s) << 16;
    return __builtin_bit_cast(float, u);
}

// ---------------------------------------------------------------------------
// k_prep_bond (grid-partitioned):
//  block 0 also computes b_ih = bi + bh (fp32).
//  blocks 0..255: weight transposes to bf16 [N=256][K].
//  blocks 256+: bondsum[atom][32] = sum_t f_bonds[a2b[atom,t], -14:]
// ---------------------------------------------------------------------------
__global__ __launch_bounds__(256) void k_prep_bond(const float* __restrict__ Wi,
                                                   const float* __restrict__ Wh,
                                                   const float* __restrict__ Wo,
                                                   const float* __restrict__ bi,
                                                   const float* __restrict__ bh,
                                                   const float* __restrict__ f_bonds,
                                                   const int* __restrict__ a2b,
                                                   unsigned short* __restrict__ Wi_t,
                                                   unsigned short* __restrict__ Wb_t,
                                                   unsigned short* __restrict__ Whm_t,
                                                   unsigned short* __restrict__ Woa_t,
                                                   unsigned short* __restrict__ Wom_t,
                                                   unsigned short* __restrict__ bondsum,
                                                   float* __restrict__ b_ih) {
    if (blockIdx.x < 256) {
        const int n = blockIdx.x;
        if (n == 0) b_ih[threadIdx.x] = bi[threadIdx.x] + bh[threadIdx.x];
        for (int k = threadIdx.x; k < KI; k += 256) {
            Wi_t[n * KI + k]  = f2bf(k < AF ? Wi[k * HID + n] : 0.f);
            Woa_t[n * KI + k] = f2bf(k < AF ? Wo[k * HID + n] : 0.f);
        }
        for (int k = threadIdx.x; k < KB; k += 256)
            Wb_t[n * KB + k] = f2bf(k < 14 ? Wh[(HID + k) * HID + n] : 0.f);
        for (int k = threadIdx.x; k < KP; k += 256) {
            Whm_t[n * KP + k] = f2bf(Wh[k * HID + n]);
            Wom_t[n * KP + k] = f2bf(Wo[(AF + k) * HID + n]);
        }
    } else {
        const int id   = (blockIdx.x - 256) * 256 + threadIdx.x;  // 1M threads
        const int atom = id >> 4;
        const int c    = id & 15;
        float s = 0.f;
        if (c < 14) {
            const int* nb = &a2b[atom * NNB];
#pragma unroll
            for (int t = 0; t < NNB; ++t)
                s += f_bonds[(size_t)nb[t] * BT + (BT - 14) + c];
        }
        bondsum[atom * 32 + c]      = f2bf(s);
        bondsum[atom * 32 + 16 + c] = 0;
    }
}

// ---------------------------------------------------------------------------
// MFMA core: C[64 x 256] += A_lds[64 x K](bf16) @ W_t[256 x K]^T
// ---------------------------------------------------------------------------
template<int K, int LS>
__device__ __forceinline__ void mfma_core(const unsigned short* __restrict__ As,
                                          const unsigned short* __restrict__ Wt,
                                          f32x4 (&acc)[4][4], int wave, int lane) {
    const int lm = lane & 15, quad = lane >> 4;
    for (int ks = 0; ks < K; ks += 32) {
        short8 af[4], bf[4];
#pragma unroll
        for (int rt = 0; rt < 4; ++rt)
            af[rt] = *(const short8*)&As[(rt * 16 + lm) * LS + ks + quad * 8];
#pragma unroll
        for (int ct = 0; ct < 4; ++ct)
            bf[ct] = *(const short8*)&Wt[(size_t)(wave * 64 + ct * 16 + lm) * K + ks + quad * 8];
#pragma unroll
        for (int rt = 0; rt < 4; ++rt)
#pragma unroll
            for (int ct = 0; ct < 4; ++ct)
                acc[rt][ct] = __builtin_amdgcn_mfma_f32_16x16x32_bf16(af[rt], bf[ct], acc[rt][ct], 0, 0, 0);
    }
}

// ---------------------------------------------------------------------------
// Epilogue: acc (C-layout) -> bf16 via LDS transpose -> coalesced short8
// stores (1 KB per wave instruction, full cacheline coverage).
// E is a 64*SE ushort LDS region (may overlay the dead A-tile).
// ---------------------------------------------------------------------------
__device__ __forceinline__ void epi_store64(f32x4 (&acc)[4][4],
                                            const float* __restrict__ bias, // may be null
                                            bool relu,
                                            unsigned short* __restrict__ dst, int base,
                                            int wave, int lane, int tid,
                                            unsigned short* __restrict__ E) {
    const int lm = lane & 15, quad = lane >> 4;
    __syncthreads();   // everyone done with whatever E overlays
#pragma unroll
    for (int ct = 0; ct < 4; ++ct) {
        int col = wave * 64 + ct * 16 + lm;
        float bv = bias ? bias[col] : 0.f;
#pragma unroll
        for (int rt = 0; rt < 4; ++rt)
#pragma unroll
            for (int i = 0; i < 4; ++i) {
                float v = acc[rt][ct][i] + bv;
                if (relu) v = fmaxf(v, 0.f);
                E[(rt * 16 + quad * 4 + i) * SE + col] = f2bf(v);
            }
    }
    __syncthreads();
    const int row = tid >> 2, chunk = (tid & 3) * 64;
#pragma unroll
    for (int j = 0; j < 8; ++j) {
        short8 v = *(const short8*)&E[row * SE + chunk + j * 8];
        *(short8*)&dst[(size_t)(base + row) * HID + chunk + j * 8] = v;
    }
}

// ---------------------------------------------------------------------------
// k_inp_a: acc = atom@Wi -> msg = relu(acc+bi);  acc += bondsum@Wb
//          -> inp2 = acc + (bi+bh).   E overlays As; Bs lives above E.
// ---------------------------------------------------------------------------
__global__ __launch_bounds__(256) void k_inp_a(const float* __restrict__ atom,
                                               const unsigned short* __restrict__ bondsum,
                                               const unsigned short* __restrict__ Wi_t,
                                               const unsigned short* __restrict__ Wb_t,
                                               const float* __restrict__ bi,
                                               const float* __restrict__ b_ih,
                                               unsigned short* __restrict__ msg,
                                               unsigned short* __restrict__ inp2) {
    __shared__ unsigned short smem[64 * SE + 64 * LSB];   // 38912 B
    unsigned short* As = smem;            // 64 x LSI (dies before E use)
    unsigned short* E  = smem;            // 64 x SE
    unsigned short* Bs = smem + 64 * SE;  // 64 x LSB
    const int tid  = threadIdx.x;
    const int base = blockIdx.x * 64;

    for (int it = tid; it < 64 * KI; it += 256) {
        int r = it / KI, c = it - r * KI;
        float v = (c < AF) ? atom[(size_t)(base + r) * AF + c] : 0.f;
        As[r * LSI + c] = f2bf(v);
    }
    {
        int r = tid >> 2, c = (tid & 3) * 8;
        *(short8*)&Bs[r * LSB + c] = *(const short8*)&bondsum[(size_t)(base + r) * 32 + c];
    }
    __syncthreads();

    const int lane = tid & 63, wave = tid >> 6;
    f32x4 acc[4][4] = {};
    mfma_core<KI, LSI>(As, Wi_t, acc, wave, lane);

    epi_store64(acc, bi, true, msg, base, wave, lane, tid, E);   // As dead now

    mfma_core<KB, LSB>(Bs, Wb_t, acc, wave, lane);
    epi_store64(acc, b_ih, false, inp2, base, wave, lane, tid, E);
}

// ---------------------------------------------------------------------------
// k_inp_b: aw = atom @ Wo_a + bo.  E overlays As.
// ---------------------------------------------------------------------------
__global__ __launch_bounds__(256) void k_inp_b(const float* __restrict__ atom,
                                               const unsigned short* __restrict__ Woa_t,
                                               const float* __restrict__ bo,
                                               unsigned short* __restrict__ aw) {
    __shared__ unsigned short smem[64 * SE];   // 33792 B
    unsigned short* As = smem;
    unsigned short* E  = smem;
    const int tid  = threadIdx.x;
    const int base = blockIdx.x * 64;

    for (int it = tid; it < 64 * KI; it += 256) {
        int r = it / KI, c = it - r * KI;
        float v = (c < AF) ? atom[(size_t)(base + r) * AF + c] : 0.f;
        As[r * LSI + c] = f2bf(v);
    }
    __syncthreads();

    const int lane = tid & 63, wave = tid >> 6;
    f32x4 acc[4][4] = {};
    mfma_core<KI, LSI>(As, Woa_t, acc, wave, lane);
    epi_store64(acc, bo, false, aw, base, wave, lane, tid, E);
}

// ---------------------------------------------------------------------------
// k_proj: P = X @ W_t^T  (dense streaming GEMM).  E overlays As.
// ---------------------------------------------------------------------------
__global__ __launch_bounds__(256, 4) void k_proj(const unsigned short* __restrict__ X,
                                                 const unsigned short* __restrict__ Wt,
                                                 unsigned short* __restrict__ P) {
    __shared__ unsigned short smem[64 * SE];
    unsigned short* As = smem;
    unsigned short* E  = smem;
    const int tid  = threadIdx.x;
    const int base = blockIdx.x * 64;

    for (int it = tid; it < 64 * 32; it += 256) {
        int r = it >> 5, ch = it & 31;
        *(short8*)&As[r * LSP + ch * 8] = *(const short8*)&X[(size_t)(base + r) * HID + ch * 8];
    }
    __syncthreads();

    const int lane = tid & 63, wave = tid >> 6;
    f32x4 acc[4][4] = {};
    mfma_core<KP, LSP>(As, Wt, acc, wave, lane);
    epi_store64(acc, nullptr, false, P, base, wave, lane, tid, E);
}

// ---------------------------------------------------------------------------
// k_gath: out[i] = relu(base_[i] + sum_t P[a2a[i,t]])
// one thread per (atom, 8-channel group); coalesced 16B loads/stores.
// ---------------------------------------------------------------------------
__global__ __launch_bounds__(256) void k_gath(const unsigned short* __restrict__ P,
                                              const unsigned short* __restrict__ base_,
                                              const int* __restrict__ a2a,
                                              unsigned short* __restrict__ out) {
    __shared__ int nb_l[8 * NNB];
    const int tid  = threadIdx.x;
    const int ablk = blockIdx.x * 8;
    if (tid < 8 * NNB) nb_l[tid] = a2a[ablk * NNB + tid];
    __syncthreads();

    const int a  = tid >> 5;
    const int cg = tid & 31;
    const int* nb = &nb_l[a * NNB];

    float s[8] = {};
#pragma unroll
    for (int t = 0; t < NNB; ++t) {
        short8 u = *(const short8*)&P[(size_t)nb[t] * HID + cg * 8];
#pragma unroll
        for (int j = 0; j < 8; ++j) s[j] += bf2f((unsigned short)u[j]);
    }
    const size_t row = (size_t)(ablk + a);
    short8 b = *(const short8*)&base_[row * HID + cg * 8];
    short8 o;
#pragma unroll
    for (int j = 0; j < 8; ++j)
        o[j] = (short)f2bf(fmaxf(s[j] + bf2f((unsigned short)b[j]), 0.f));
    *(short8*)&out[row * HID + cg * 8] = o;
}

// ---------------------------------------------------------------------------
// k_segmean: segment mean over sorted segment_ids, one block per molecule.
// ---------------------------------------------------------------------------
__global__ __launch_bounds__(256) void k_segmean(const unsigned short* __restrict__ hid,
                                                 const int* __restrict__ seg,
                                                 float* __restrict__ out) {
    const int m = blockIdx.x;
    __shared__ int lohi[2];
    if (threadIdx.x == 0) {
        int lo = 0, hi = N_ATOMS;
        while (lo < hi) { int mid = (lo + hi) >> 1; if (seg[mid] < m) lo = mid + 1; else hi = mid; }
        lohi[0] = lo;
        int lo2 = lo, hi2 = N_ATOMS;
        while (lo2 < hi2) { int mid = (lo2 + hi2) >> 1; if (seg[mid] < m + 1) lo2 = mid + 1; else hi2 = mid; }
        lohi[1] = lo2;
    }
    __syncthreads();
    const int lo = lohi[0], hi = lohi[1];
    const int j = threadIdx.x;
    float s = 0.f;
    for (int i = lo; i < hi; ++i) s += bf2f(hid[(size_t)i * HID + j]);
    const int cnt = hi - lo;
    out[m * HID + j] = (cnt > 0) ? (s / (float)cnt) : 0.f;
}

// ---------------------------------------------------------------------------
extern "C" void kernel_launch(void* const* d_in, const int* in_sizes, int n_in,
                              void* d_out, int out_size, void* d_ws, size_t ws_size,
                              hipStream_t stream) {
    const float* atom    = (const float*)d_in[0];
    const float* f_bonds = (const float*)d_in[1];
    const int*   a2a     = (const int*)d_in[2];
    const int*   a2b     = (const int*)d_in[3];
    const int*   seg     = (const int*)d_in[4];
    const float* Wi      = (const float*)d_in[5];
    const float* bi      = (const float*)d_in[6];
    const float* Wh      = (const float*)d_in[7];
    const float* bh      = (const float*)d_in[8];
    const float* Wo      = (const float*)d_in[9];
    const float* bo      = (const float*)d_in[10];
    float* out = (float*)d_out;

    unsigned short* ws = (unsigned short*)d_ws;
    const size_t nh = (size_t)N_ATOMS * HID;
    unsigned short* msg0 = ws;               // 32 MB
    unsigned short* msg1 = msg0 + nh;        // 32 MB
    unsigned short* inp2 = msg1 + nh;        // 32 MB
    unsigned short* aw   = inp2 + nh;        // 32 MB
    unsigned short* P    = aw + nh;          // 32 MB
    unsigned short* bsum = P + nh;           // 4 MB
    unsigned short* Wi_t  = bsum + (size_t)N_ATOMS * 32;
    unsigned short* Wb_t  = Wi_t + 256 * KI;
    unsigned short* Whm_t = Wb_t + 256 * KB;
    unsigned short* Woa_t = Whm_t + 256 * KP;
    unsigned short* Wom_t = Woa_t + 256 * KI;
    float*          b_ih  = (float*)(Wom_t + 256 * KP);   // 256 fp32

    dim3 blk(256);

    k_prep_bond<<<256 + N_ATOMS * 16 / 256, blk, 0, stream>>>(
        Wi, Wh, Wo, bi, bh, f_bonds, a2b,
        Wi_t, Wb_t, Whm_t, Woa_t, Wom_t, bsum, b_ih);
    k_inp_a<<<N_ATOMS / 64, blk, 0, stream>>>(atom, bsum, Wi_t, Wb_t, bi, b_ih, msg0, inp2);
    k_inp_b<<<N_ATOMS / 64, blk, 0, stream>>>(atom, Woa_t, bo, aw);

    k_proj<<<N_ATOMS / 64, blk, 0, stream>>>(msg0, Whm_t, P);
    k_gath<<<N_ATOMS / 8, blk, 0, stream>>>(P, inp2, a2a, msg1);

    k_proj<<<N_ATOMS / 64, blk, 0, stream>>>(msg1, Whm_t, P);
    k_gath<<<N_ATOMS / 8, blk, 0, stream>>>(P, inp2, a2a, msg0);

    k_proj<<<N_ATOMS / 64, blk, 0, stream>>>(msg0, Wom_t, P);
    k_gath<<<N_ATOMS / 8, blk, 0, stream>>>(P, aw, a2a, msg1);   // hid

    k_segmean<<<NM, blk, 0, stream>>>(msg1, seg, out);
}

// Round 6
// 414.692 us; speedup vs baseline: 1.1522x; 1.1522x over previous
//
#include <hip/hip_runtime.h>

#define N_ATOMS 65536
#define AF      133
#define BT      147
#define HID     256
#define NNB     6
#define NM      2048

#define KI   160        // atom(133) padded
#define KB   32         // bond(14) padded
#define KP   256        // msg-side GEMMs (exact)
// LDS strides (elements)
#define LSI  168
#define LSB  40
#define LSP  264

typedef __attribute__((ext_vector_type(8))) short short8;
typedef __attribute__((ext_vector_type(4))) float f32x4;

__device__ __forceinline__ unsigned short f2bf(float f) {
    unsigned u = __builtin_bit_cast(unsigned, f);
    u += 0x7fffu + ((u >> 16) & 1u);
    return (unsigned short)(u >> 16);
}
__device__ __forceinline__ float bf2f(unsigned short s) {
    unsigned u = ((unsigned)s) << 16;
    return __builtin_bit_cast(float, u);
}

// ---------------------------------------------------------------------------
// k_prep_bond: weight transposes (bf16 [N][K]) + b_ih + bondsum gather.
// ---------------------------------------------------------------------------
__global__ __launch_bounds__(256) void k_prep_bond(const float* __restrict__ Wi,
                                                   const float* __restrict__ Wh,
                                                   const float* __restrict__ Wo,
                                                   const float* __restrict__ bi,
                                                   const float* __restrict__ bh,
                                                   const float* __restrict__ f_bonds,
                                                   const int* __restrict__ a2b,
                                                   unsigned short* __restrict__ Wi_t,
                                                   unsigned short* __restrict__ Wb_t,
                                                   unsigned short* __restrict__ Whm_t,
                                                   unsigned short* __restrict__ Woa_t,
                                                   unsigned short* __restrict__ Wom_t,
                                                   unsigned short* __restrict__ bondsum,
                                                   float* __restrict__ b_ih) {
    if (blockIdx.x < 256) {
        const int n = blockIdx.x;
        if (n == 0) b_ih[threadIdx.x] = bi[threadIdx.x] + bh[threadIdx.x];
        for (int k = threadIdx.x; k < KI; k += 256) {
            Wi_t[n * KI + k]  = f2bf(k < AF ? Wi[k * HID + n] : 0.f);
            Woa_t[n * KI + k] = f2bf(k < AF ? Wo[k * HID + n] : 0.f);
        }
        for (int k = threadIdx.x; k < KB; k += 256)
            Wb_t[n * KB + k] = f2bf(k < 14 ? Wh[(HID + k) * HID + n] : 0.f);
        for (int k = threadIdx.x; k < KP; k += 256) {
            Whm_t[n * KP + k] = f2bf(Wh[k * HID + n]);
            Wom_t[n * KP + k] = f2bf(Wo[(AF + k) * HID + n]);
        }
    } else {
        const int id   = (blockIdx.x - 256) * 256 + threadIdx.x;
        const int atom = id >> 4;
        const int c    = id & 15;
        float s = 0.f;
        if (c < 14) {
            const int* nb = &a2b[atom * NNB];
#pragma unroll
            for (int t = 0; t < NNB; ++t)
                s += f_bonds[(size_t)nb[t] * BT + (BT - 14) + c];
        }
        bondsum[atom * 32 + c]      = f2bf(s);
        bondsum[atom * 32 + 16 + c] = 0;
    }
}

// ---------------------------------------------------------------------------
// MFMA core (RT row-tiles of 16): C += A_lds[RT*16 x K] @ W_t[256 x K]^T
// ---------------------------------------------------------------------------
template<int K, int LS, int RT>
__device__ __forceinline__ void mfma_core(const unsigned short* __restrict__ As,
                                          const unsigned short* __restrict__ Wt,
                                          f32x4 (&acc)[RT][4], int wave, int lane) {
    const int lm = lane & 15, quad = lane >> 4;
    for (int ks = 0; ks < K; ks += 32) {
        short8 af[RT], bf[4];
#pragma unroll
        for (int rt = 0; rt < RT; ++rt)
            af[rt] = *(const short8*)&As[(rt * 16 + lm) * LS + ks + quad * 8];
#pragma unroll
        for (int ct = 0; ct < 4; ++ct)
            bf[ct] = *(const short8*)&Wt[(size_t)(wave * 64 + ct * 16 + lm) * K + ks + quad * 8];
#pragma unroll
        for (int rt = 0; rt < RT; ++rt)
#pragma unroll
            for (int ct = 0; ct < 4; ++ct)
                acc[rt][ct] = __builtin_amdgcn_mfma_f32_16x16x32_bf16(af[rt], bf[ct], acc[rt][ct], 0, 0, 0);
    }
}

// C-layout acc -> bf16 tile in LDS (rows 0..31, stride LSP)
__device__ __forceinline__ void epi_to_lds(f32x4 (&acc)[2][4],
                                           const float* __restrict__ bias,
                                           bool relu_,
                                           unsigned short* __restrict__ E,
                                           int wave, int lane) {
    const int lm = lane & 15, quad = lane >> 4;
#pragma unroll
    for (int ct = 0; ct < 4; ++ct) {
        int col = wave * 64 + ct * 16 + lm;
        float bv = bias ? bias[col] : 0.f;
#pragma unroll
        for (int rt = 0; rt < 2; ++rt)
#pragma unroll
            for (int i = 0; i < 4; ++i) {
                float v = acc[rt][ct][i] + bv;
                if (relu_) v = fmaxf(v, 0.f);
                E[(rt * 16 + quad * 4 + i) * LSP + col] = f2bf(v);
            }
    }
}

// coalesced 16B row-major store of a 32x256 LDS tile
__device__ __forceinline__ void store_tile32(unsigned short* __restrict__ dst, int base,
                                             const unsigned short* __restrict__ E, int tid) {
#pragma unroll
    for (int k = 0; k < 4; ++k) {
        int j = k * 256 + tid;
        int r = j >> 5, g = j & 31;
        *(short8*)&dst[(size_t)(base + r) * HID + g * 8] = *(const short8*)&E[r * LSP + g * 8];
    }
}

// ---------------------------------------------------------------------------
// k_inp (32-row tiles):
//   acc1 = atom@Wi  -> m = relu(acc1+bi) (LDS only)
//   acc2 = m@Whm    -> P0
//   acc1 += bondsum@Wb -> inp2 = acc1 + (bi+bh)
// ---------------------------------------------------------------------------
__global__ __launch_bounds__(256) void k_inp(const float* __restrict__ atom,
                                             const unsigned short* __restrict__ bondsum,
                                             const unsigned short* __restrict__ Wi_t,
                                             const unsigned short* __restrict__ Wb_t,
                                             const unsigned short* __restrict__ Whm_t,
                                             const float* __restrict__ bi,
                                             const float* __restrict__ b_ih,
                                             unsigned short* __restrict__ P0,
                                             unsigned short* __restrict__ inp2) {
    __shared__ unsigned short R1[32 * LSP];   // atomT+bs, later E for P0
    __shared__ unsigned short mT[32 * LSP];   // m tile, later E for inp2
    unsigned short* atomT = R1;
    unsigned short* bs    = R1 + 32 * LSI;
    const int tid  = threadIdx.x;
    const int base = blockIdx.x * 32;

    for (int it = tid; it < 32 * KI; it += 256) {
        int r = it / KI, c = it - r * KI;
        float v = (c < AF) ? atom[(size_t)(base + r) * AF + c] : 0.f;
        atomT[r * LSI + c] = f2bf(v);
    }
    if (tid < 128) {
        int r = tid >> 2, c = (tid & 3) * 8;
        *(short8*)&bs[r * LSB + c] = *(const short8*)&bondsum[(size_t)(base + r) * 32 + c];
    }
    __syncthreads();

    const int lane = tid & 63, wave = tid >> 6;
    f32x4 acc1[2][4] = {};
    mfma_core<KI, LSI, 2>(atomT, Wi_t, acc1, wave, lane);

    epi_to_lds(acc1, bi, true, mT, wave, lane);           // m = relu(inp)
    __syncthreads();

    f32x4 acc2[2][4] = {};
    mfma_core<KP, LSP, 2>(mT, Whm_t, acc2, wave, lane);   // P0 = m @ Whm
    mfma_core<KB, LSB, 2>(bs, Wb_t, acc1, wave, lane);    // + bond part
    __syncthreads();                                      // atomT/bs/mT reads done

    epi_to_lds(acc2, nullptr, false, R1, wave, lane);     // P0 tile
    epi_to_lds(acc1, b_ih, false, mT, wave, lane);        // inp2 tile
    __syncthreads();
    store_tile32(P0,   base, R1, tid);
    store_tile32(inp2, base, mT, tid);
}

// ---------------------------------------------------------------------------
// k_inp_b (32-row tiles): aw = atom @ Wo_a + bo
// ---------------------------------------------------------------------------
__global__ __launch_bounds__(256) void k_inp_b(const float* __restrict__ atom,
                                               const unsigned short* __restrict__ Woa_t,
                                               const float* __restrict__ bo,
                                               unsigned short* __restrict__ aw) {
    __shared__ unsigned short R[32 * LSP];
    const int tid  = threadIdx.x;
    const int base = blockIdx.x * 32;

    for (int it = tid; it < 32 * KI; it += 256) {
        int r = it / KI, c = it - r * KI;
        float v = (c < AF) ? atom[(size_t)(base + r) * AF + c] : 0.f;
        R[r * LSI + c] = f2bf(v);
    }
    __syncthreads();

    const int lane = tid & 63, wave = tid >> 6;
    f32x4 acc[2][4] = {};
    mfma_core<KI, LSI, 2>(R, Woa_t, acc, wave, lane);
    __syncthreads();
    epi_to_lds(acc, bo, false, R, wave, lane);
    __syncthreads();
    store_tile32(aw, base, R, tid);
}

// ---------------------------------------------------------------------------
// k_it (fused gather+proj, 32-row tiles):
//   m = relu(base_ + sum_t Pin[a2a[.,t]])  (LDS only)
//   Pout = m @ Wt
// ---------------------------------------------------------------------------
__global__ __launch_bounds__(256) void k_it(const unsigned short* __restrict__ Pin,
                                            const unsigned short* __restrict__ base_,
                                            const int* __restrict__ a2a,
                                            const unsigned short* __restrict__ Wt,
                                            unsigned short* __restrict__ Pout) {
    __shared__ unsigned short mT[32 * LSP];
    __shared__ int nb_l[32 * NNB];
    const int tid  = threadIdx.x;
    const int base = blockIdx.x * 32;

    if (tid < 32 * NNB) nb_l[tid] = a2a[base * NNB + tid];
    __syncthreads();

#pragma unroll
    for (int k = 0; k < 4; ++k) {
        int j = k * 256 + tid;
        int r = j >> 5, g = j & 31;
        const int* nb = &nb_l[r * NNB];
        float s[8] = {};
#pragma unroll
        for (int t = 0; t < NNB; ++t) {
            short8 u = *(const short8*)&Pin[(size_t)nb[t] * HID + g * 8];
#pragma unroll
            for (int q = 0; q < 8; ++q) s[q] += bf2f((unsigned short)u[q]);
        }
        short8 b = *(const short8*)&base_[(size_t)(base + r) * HID + g * 8];
        short8 o;
#pragma unroll
        for (int q = 0; q < 8; ++q)
            o[q] = (short)f2bf(fmaxf(s[q] + bf2f((unsigned short)b[q]), 0.f));
        *(short8*)&mT[r * LSP + g * 8] = o;
    }
    __syncthreads();

    const int lane = tid & 63, wave = tid >> 6;
    f32x4 acc[2][4] = {};
    mfma_core<KP, LSP, 2>(mT, Wt, acc, wave, lane);
    __syncthreads();
    epi_to_lds(acc, nullptr, false, mT, wave, lane);
    __syncthreads();
    store_tile32(Pout, base, mT, tid);
}

// ---------------------------------------------------------------------------
// k_gath: hid[i] = relu(aw[i] + sum_t P[a2a[i,t]])
// ---------------------------------------------------------------------------
__global__ __launch_bounds__(256) void k_gath(const unsigned short* __restrict__ P,
                                              const unsigned short* __restrict__ base_,
                                              const int* __restrict__ a2a,
                                              unsigned short* __restrict__ out) {
    __shared__ int nb_l[8 * NNB];
    const int tid  = threadIdx.x;
    const int ablk = blockIdx.x * 8;
    if (tid < 8 * NNB) nb_l[tid] = a2a[ablk * NNB + tid];
    __syncthreads();

    const int a  = tid >> 5;
    const int cg = tid & 31;
    const int* nb = &nb_l[a * NNB];

    float s[8] = {};
#pragma unroll
    for (int t = 0; t < NNB; ++t) {
        short8 u = *(const short8*)&P[(size_t)nb[t] * HID + cg * 8];
#pragma unroll
        for (int j = 0; j < 8; ++j) s[j] += bf2f((unsigned short)u[j]);
    }
    const size_t row = (size_t)(ablk + a);
    short8 b = *(const short8*)&base_[row * HID + cg * 8];
    short8 o;
#pragma unroll
    for (int j = 0; j < 8; ++j)
        o[j] = (short)f2bf(fmaxf(s[j] + bf2f((unsigned short)b[j]), 0.f));
    *(short8*)&out[row * HID + cg * 8] = o;
}

// ---------------------------------------------------------------------------
// k_segmean: segment mean over sorted segment_ids.
// ---------------------------------------------------------------------------
__global__ __launch_bounds__(256) void k_segmean(const unsigned short* __restrict__ hid,
                                                 const int* __restrict__ seg,
                                                 float* __restrict__ out) {
    const int m = blockIdx.x;
    __shared__ int lohi[2];
    if (threadIdx.x == 0) {
        int lo = 0, hi = N_ATOMS;
        while (lo < hi) { int mid = (lo + hi) >> 1; if (seg[mid] < m) lo = mid + 1; else hi = mid; }
        lohi[0] = lo;
        int lo2 = lo, hi2 = N_ATOMS;
        while (lo2 < hi2) { int mid = (lo2 + hi2) >> 1; if (seg[mid] < m + 1) lo2 = mid + 1; else hi2 = mid; }
        lohi[1] = lo2;
    }
    __syncthreads();
    const int lo = lohi[0], hi = lohi[1];
    const int j = threadIdx.x;
    float s = 0.f;
    for (int i = lo; i < hi; ++i) s += bf2f(hid[(size_t)i * HID + j]);
    const int cnt = hi - lo;
    out[m * HID + j] = (cnt > 0) ? (s / (float)cnt) : 0.f;
}

// ---------------------------------------------------------------------------
extern "C" void kernel_launch(void* const* d_in, const int* in_sizes, int n_in,
                              void* d_out, int out_size, void* d_ws, size_t ws_size,
                              hipStream_t stream) {
    const float* atom    = (const float*)d_in[0];
    const float* f_bonds = (const float*)d_in[1];
    const int*   a2a     = (const int*)d_in[2];
    const int*   a2b     = (const int*)d_in[3];
    const int*   seg     = (const int*)d_in[4];
    const float* Wi      = (const float*)d_in[5];
    const float* bi      = (const float*)d_in[6];
    const float* Wh      = (const float*)d_in[7];
    const float* bh      = (const float*)d_in[8];
    const float* Wo      = (const float*)d_in[9];
    const float* bo      = (const float*)d_in[10];
    float* out = (float*)d_out;

    unsigned short* ws = (unsigned short*)d_ws;
    const size_t nh = (size_t)N_ATOMS * HID;
    unsigned short* Pa   = ws;               // 32 MB
    unsigned short* Pb   = Pa + nh;          // 32 MB
    unsigned short* inp2 = Pb + nh;          // 32 MB
    unsigned short* aw   = inp2 + nh;        // 32 MB
    unsigned short* bsum = aw + nh;          // 4 MB
    unsigned short* Wi_t  = bsum + (size_t)N_ATOMS * 32;
    unsigned short* Wb_t  = Wi_t + 256 * KI;
    unsigned short* Whm_t = Wb_t + 256 * KB;
    unsigned short* Woa_t = Whm_t + 256 * KP;
    unsigned short* Wom_t = Woa_t + 256 * KI;
    float*          b_ih  = (float*)(Wom_t + 256 * KP);

    dim3 blk(256);
    const int nb32 = N_ATOMS / 32;   // 2048

    k_prep_bond<<<256 + N_ATOMS * 16 / 256, blk, 0, stream>>>(
        Wi, Wh, Wo, bi, bh, f_bonds, a2b,
        Wi_t, Wb_t, Whm_t, Woa_t, Wom_t, bsum, b_ih);
    k_inp_b<<<nb32, blk, 0, stream>>>(atom, Woa_t, bo, aw);
    k_inp<<<nb32, blk, 0, stream>>>(atom, bsum, Wi_t, Wb_t, Whm_t, bi, b_ih, Pa, inp2);

    k_it<<<nb32, blk, 0, stream>>>(Pa, inp2, a2a, Whm_t, Pb);   // -> P1
    k_it<<<nb32, blk, 0, stream>>>(Pb, inp2, a2a, Wom_t, Pa);   // -> P2
    k_gath<<<N_ATOMS / 8, blk, 0, stream>>>(Pa, aw, a2a, Pb);   // -> hid

    k_segmean<<<NM, blk, 0, stream>>>(Pb, seg, out);
}

// Round 7
// 385.362 us; speedup vs baseline: 1.2399x; 1.0761x over previous
//
#include <hip/hip_runtime.h>

#define N_ATOMS 65536
#define AF      133
#define BT      147
#define HID     256
#define NNB     6
#define NM      2048

#define KI   160        // atom(133) padded
#define KB   32         // bond(14) padded
#define KP   256        // msg-side GEMMs (exact)
// LDS strides (elements)
#define LSI  168
#define LSB  40
#define LSP  264

typedef __attribute__((ext_vector_type(8))) short short8;
typedef __attribute__((ext_vector_type(4))) float f32x4;

__device__ __forceinline__ unsigned short f2bf(float f) {
    unsigned u = __builtin_bit_cast(unsigned, f);
    u += 0x7fffu + ((u >> 16) & 1u);
    return (unsigned short)(u >> 16);
}
__device__ __forceinline__ float bf2f(unsigned short s) {
    unsigned u = ((unsigned)s) << 16;
    return __builtin_bit_cast(float, u);
}

// ---------------------------------------------------------------------------
// k_prep_bond: weight transposes (bf16 [N][K]) + b_ih + bondsum gather.
// ---------------------------------------------------------------------------
__global__ __launch_bounds__(256) void k_prep_bond(const float* __restrict__ Wi,
                                                   const float* __restrict__ Wh,
                                                   const float* __restrict__ Wo,
                                                   const float* __restrict__ bi,
                                                   const float* __restrict__ bh,
                                                   const float* __restrict__ f_bonds,
                                                   const int* __restrict__ a2b,
                                                   unsigned short* __restrict__ Wi_t,
                                                   unsigned short* __restrict__ Wb_t,
                                                   unsigned short* __restrict__ Whm_t,
                                                   unsigned short* __restrict__ Woa_t,
                                                   unsigned short* __restrict__ Wom_t,
                                                   unsigned short* __restrict__ bondsum,
                                                   float* __restrict__ b_ih) {
    if (blockIdx.x < 256) {
        const int n = blockIdx.x;
        if (n == 0) b_ih[threadIdx.x] = bi[threadIdx.x] + bh[threadIdx.x];
        for (int k = threadIdx.x; k < KI; k += 256) {
            Wi_t[n * KI + k]  = f2bf(k < AF ? Wi[k * HID + n] : 0.f);
            Woa_t[n * KI + k] = f2bf(k < AF ? Wo[k * HID + n] : 0.f);
        }
        for (int k = threadIdx.x; k < KB; k += 256)
            Wb_t[n * KB + k] = f2bf(k < 14 ? Wh[(HID + k) * HID + n] : 0.f);
        for (int k = threadIdx.x; k < KP; k += 256) {
            Whm_t[n * KP + k] = f2bf(Wh[k * HID + n]);
            Wom_t[n * KP + k] = f2bf(Wo[(AF + k) * HID + n]);
        }
    } else {
        const int id   = (blockIdx.x - 256) * 256 + threadIdx.x;
        const int atom = id >> 4;
        const int c    = id & 15;
        float s = 0.f;
        if (c < 14) {
            const int* nb = &a2b[atom * NNB];
#pragma unroll
            for (int t = 0; t < NNB; ++t)
                s += f_bonds[(size_t)nb[t] * BT + (BT - 14) + c];
        }
        bondsum[atom * 32 + c]      = f2bf(s);
        bondsum[atom * 32 + 16 + c] = 0;
    }
}

// ---------------------------------------------------------------------------
// MFMA core (RT row-tiles of 16): C += A_lds[RT*16 x K] @ W_t[256 x K]^T
// ---------------------------------------------------------------------------
template<int K, int LS, int RT>
__device__ __forceinline__ void mfma_core(const unsigned short* __restrict__ As,
                                          const unsigned short* __restrict__ Wt,
                                          f32x4 (&acc)[RT][4], int wave, int lane) {
    const int lm = lane & 15, quad = lane >> 4;
    for (int ks = 0; ks < K; ks += 32) {
        short8 af[RT], bf[4];
#pragma unroll
        for (int rt = 0; rt < RT; ++rt)
            af[rt] = *(const short8*)&As[(rt * 16 + lm) * LS + ks + quad * 8];
#pragma unroll
        for (int ct = 0; ct < 4; ++ct)
            bf[ct] = *(const short8*)&Wt[(size_t)(wave * 64 + ct * 16 + lm) * K + ks + quad * 8];
#pragma unroll
        for (int rt = 0; rt < RT; ++rt)
#pragma unroll
            for (int ct = 0; ct < 4; ++ct)
                acc[rt][ct] = __builtin_amdgcn_mfma_f32_16x16x32_bf16(af[rt], bf[ct], acc[rt][ct], 0, 0, 0);
    }
}

// C-layout acc -> bf16 tile in LDS (rows 0..31, stride LSP)
__device__ __forceinline__ void epi_to_lds(f32x4 (&acc)[2][4],
                                           const float* __restrict__ bias,
                                           bool relu_,
                                           unsigned short* __restrict__ E,
                                           int wave, int lane) {
    const int lm = lane & 15, quad = lane >> 4;
#pragma unroll
    for (int ct = 0; ct < 4; ++ct) {
        int col = wave * 64 + ct * 16 + lm;
        float bv = bias ? bias[col] : 0.f;
#pragma unroll
        for (int rt = 0; rt < 2; ++rt)
#pragma unroll
            for (int i = 0; i < 4; ++i) {
                float v = acc[rt][ct][i] + bv;
                if (relu_) v = fmaxf(v, 0.f);
                E[(rt * 16 + quad * 4 + i) * LSP + col] = f2bf(v);
            }
    }
}

// coalesced 16B row-major store of a 32x256 LDS tile
__device__ __forceinline__ void store_tile32(unsigned short* __restrict__ dst, int base,
                                             const unsigned short* __restrict__ E, int tid) {
#pragma unroll
    for (int k = 0; k < 4; ++k) {
        int j = k * 256 + tid;
        int r = j >> 5, g = j & 31;
        *(short8*)&dst[(size_t)(base + r) * HID + g * 8] = *(const short8*)&E[r * LSP + g * 8];
    }
}

// ---------------------------------------------------------------------------
// k_inp (32-row tiles), fully fused front-end:
//   acc1 = atom@Wi          ; acc3 = atom@Wo_a
//   mT   = relu(acc1 + bi)  (LDS, overlays atom tile)
//   acc2 = mT@Whm  -> P0    ; acc1 += bondsum@Wb -> inp2 = acc1 + (bi+bh)
//   aw   = acc3 + bo
// ---------------------------------------------------------------------------
__global__ __launch_bounds__(256, 4) void k_inp(const float* __restrict__ atom,
                                                const unsigned short* __restrict__ bondsum,
                                                const unsigned short* __restrict__ Wi_t,
                                                const unsigned short* __restrict__ Wb_t,
                                                const unsigned short* __restrict__ Whm_t,
                                                const unsigned short* __restrict__ Woa_t,
                                                const float* __restrict__ bi,
                                                const float* __restrict__ b_ih,
                                                const float* __restrict__ bo,
                                                unsigned short* __restrict__ P0,
                                                unsigned short* __restrict__ inp2,
                                                unsigned short* __restrict__ aw) {
    __shared__ unsigned short big[32 * LSP];   // atomT -> mT -> epilogue tile
    __shared__ unsigned short bs[32 * LSB];
    const int tid  = threadIdx.x;
    const int base = blockIdx.x * 32;

    for (int it = tid; it < 32 * KI; it += 256) {
        int r = it / KI, c = it - r * KI;
        big[r * LSI + c] = f2bf(c < AF ? atom[(size_t)(base + r) * AF + c] : 0.f);
    }
    if (tid < 128) {
        int r = tid >> 2, c = (tid & 3) * 8;
        *(short8*)&bs[r * LSB + c] = *(const short8*)&bondsum[(size_t)(base + r) * 32 + c];
    }
    __syncthreads();

    const int lane = tid & 63, wave = tid >> 6;
    f32x4 acc1[2][4] = {}, acc3[2][4] = {};
    mfma_core<KI, LSI, 2>(big, Wi_t,  acc1, wave, lane);
    mfma_core<KI, LSI, 2>(big, Woa_t, acc3, wave, lane);
    __syncthreads();                                   // atomT reads done

    epi_to_lds(acc1, bi, true, big, wave, lane);       // mT = relu(inp)
    __syncthreads();

    f32x4 acc2[2][4] = {};
    mfma_core<KP, LSP, 2>(big, Whm_t, acc2, wave, lane);  // P0 = m @ Whm
    mfma_core<KB, LSB, 2>(bs,  Wb_t,  acc1, wave, lane);  // + bond part
    __syncthreads();                                   // mT reads done

    epi_to_lds(acc2, nullptr, false, big, wave, lane);
    __syncthreads();
    store_tile32(P0, base, big, tid);
    __syncthreads();
    epi_to_lds(acc1, b_ih, false, big, wave, lane);
    __syncthreads();
    store_tile32(inp2, base, big, tid);
    __syncthreads();
    epi_to_lds(acc3, bo, false, big, wave, lane);
    __syncthreads();
    store_tile32(aw, base, big, tid);
}

// ---------------------------------------------------------------------------
// k_it (fused gather+proj, 32-row tiles):
//   m = relu(base_ + sum_t Pin[a2a[.,t]])  (LDS only)
//   Pout = m @ Wt
// ---------------------------------------------------------------------------
__global__ __launch_bounds__(256) void k_it(const unsigned short* __restrict__ Pin,
                                            const unsigned short* __restrict__ base_,
                                            const int* __restrict__ a2a,
                                            const unsigned short* __restrict__ Wt,
                                            unsigned short* __restrict__ Pout) {
    __shared__ unsigned short mT[32 * LSP];
    __shared__ int nb_l[32 * NNB];
    const int tid  = threadIdx.x;
    const int base = blockIdx.x * 32;

    if (tid < 32 * NNB) nb_l[tid] = a2a[base * NNB + tid];
    __syncthreads();

#pragma unroll
    for (int k = 0; k < 4; ++k) {
        int j = k * 256 + tid;
        int r = j >> 5, g = j & 31;
        const int* nb = &nb_l[r * NNB];
        float s[8] = {};
#pragma unroll
        for (int t = 0; t < NNB; ++t) {
            short8 u = *(const short8*)&Pin[(size_t)nb[t] * HID + g * 8];
#pragma unroll
            for (int q = 0; q < 8; ++q) s[q] += bf2f((unsigned short)u[q]);
        }
        short8 b = *(const short8*)&base_[(size_t)(base + r) * HID + g * 8];
        short8 o;
#pragma unroll
        for (int q = 0; q < 8; ++q)
            o[q] = (short)f2bf(fmaxf(s[q] + bf2f((unsigned short)b[q]), 0.f));
        *(short8*)&mT[r * LSP + g * 8] = o;
    }
    __syncthreads();

    const int lane = tid & 63, wave = tid >> 6;
    f32x4 acc[2][4] = {};
    mfma_core<KP, LSP, 2>(mT, Wt, acc, wave, lane);
    __syncthreads();
    epi_to_lds(acc, nullptr, false, mT, wave, lane);
    __syncthreads();
    store_tile32(Pout, base, mT, tid);
}

// ---------------------------------------------------------------------------
// k_gseg (fused final gather + segment mean): one block per molecule.
//   out[m][j] = mean_i relu(aw[i][j] + sum_t P[a2a[i,t]][j])  over i in seg m
// ---------------------------------------------------------------------------
__global__ __launch_bounds__(256) void k_gseg(const unsigned short* __restrict__ P,
                                              const unsigned short* __restrict__ aw,
                                              const int* __restrict__ a2a,
                                              const int* __restrict__ seg,
                                              float* __restrict__ out) {
    const int m = blockIdx.x;
    __shared__ int lohi[2];
    if (threadIdx.x == 0) {
        int lo = 0, hi = N_ATOMS;
        while (lo < hi) { int mid = (lo + hi) >> 1; if (seg[mid] < m) lo = mid + 1; else hi = mid; }
        lohi[0] = lo;
        int lo2 = lo, hi2 = N_ATOMS;
        while (lo2 < hi2) { int mid = (lo2 + hi2) >> 1; if (seg[mid] < m + 1) lo2 = mid + 1; else hi2 = mid; }
        lohi[1] = lo2;
    }
    __syncthreads();
    const int lo = lohi[0], hi = lohi[1];
    const int j = threadIdx.x;
    float s = 0.f;
#pragma unroll 2
    for (int i = lo; i < hi; ++i) {
        const int* nb = &a2a[i * NNB];
        float v = bf2f(aw[(size_t)i * HID + j]);
#pragma unroll
        for (int t = 0; t < NNB; ++t)
            v += bf2f(P[(size_t)nb[t] * HID + j]);
        s += fmaxf(v, 0.f);
    }
    const int cnt = hi - lo;
    out[m * HID + j] = (cnt > 0) ? (s / (float)cnt) : 0.f;
}

// ---------------------------------------------------------------------------
extern "C" void kernel_launch(void* const* d_in, const int* in_sizes, int n_in,
                              void* d_out, int out_size, void* d_ws, size_t ws_size,
                              hipStream_t stream) {
    const float* atom    = (const float*)d_in[0];
    const float* f_bonds = (const float*)d_in[1];
    const int*   a2a     = (const int*)d_in[2];
    const int*   a2b     = (const int*)d_in[3];
    const int*   seg     = (const int*)d_in[4];
    const float* Wi      = (const float*)d_in[5];
    const float* bi      = (const float*)d_in[6];
    const float* Wh      = (const float*)d_in[7];
    const float* bh      = (const float*)d_in[8];
    const float* Wo      = (const float*)d_in[9];
    const float* bo      = (const float*)d_in[10];
    float* out = (float*)d_out;

    unsigned short* ws = (unsigned short*)d_ws;
    const size_t nh = (size_t)N_ATOMS * HID;
    unsigned short* Pa   = ws;               // 32 MB
    unsigned short* Pb   = Pa + nh;          // 32 MB
    unsigned short* inp2 = Pb + nh;          // 32 MB
    unsigned short* aw   = inp2 + nh;        // 32 MB
    unsigned short* bsum = aw + nh;          // 4 MB
    unsigned short* Wi_t  = bsum + (size_t)N_ATOMS * 32;
    unsigned short* Wb_t  = Wi_t + 256 * KI;
    unsigned short* Whm_t = Wb_t + 256 * KB;
    unsigned short* Woa_t = Whm_t + 256 * KP;
    unsigned short* Wom_t = Woa_t + 256 * KI;
    float*          b_ih  = (float*)(Wom_t + 256 * KP);

    dim3 blk(256);
    const int nb32 = N_ATOMS / 32;   // 2048

    k_prep_bond<<<256 + N_ATOMS * 16 / 256, blk, 0, stream>>>(
        Wi, Wh, Wo, bi, bh, f_bonds, a2b,
        Wi_t, Wb_t, Whm_t, Woa_t, Wom_t, bsum, b_ih);
    k_inp<<<nb32, blk, 0, stream>>>(atom, bsum, Wi_t, Wb_t, Whm_t, Woa_t,
                                    bi, b_ih, bo, Pa, inp2, aw);

    k_it<<<nb32, blk, 0, stream>>>(Pa, inp2, a2a, Whm_t, Pb);   // -> P1
    k_it<<<nb32, blk, 0, stream>>>(Pb, inp2, a2a, Wom_t, Pa);   // -> P2
    k_gseg<<<NM, blk, 0, stream>>>(Pa, aw, a2a, seg, out);
}

// Round 8
// 375.783 us; speedup vs baseline: 1.2715x; 1.0255x over previous
//
#include <hip/hip_runtime.h>

#define N_ATOMS 65536
#define AF      133
#define BT      147
#define HID     256
#define NNB     6
#define NM      2048

#define KI   160        // atom(133) padded
#define KB   32         // bond(14) padded
#define KP   256        // msg-side GEMMs (exact)
// LDS strides (elements)
#define LSI  168
#define LSB  40
#define LSP  264

typedef __attribute__((ext_vector_type(8))) short short8;
typedef __attribute__((ext_vector_type(4))) float f32x4;

__device__ __forceinline__ unsigned short f2bf(float f) {
    unsigned u = __builtin_bit_cast(unsigned, f);
    u += 0x7fffu + ((u >> 16) & 1u);
    return (unsigned short)(u >> 16);
}
__device__ __forceinline__ float bf2f(unsigned short s) {
    unsigned u = ((unsigned)s) << 16;
    return __builtin_bit_cast(float, u);
}

// ---------------------------------------------------------------------------
// k_prep_bond: weight transposes (bf16 [N][K]) + b_ih + bondsum gather.
// ---------------------------------------------------------------------------
__global__ __launch_bounds__(256) void k_prep_bond(const float* __restrict__ Wi,
                                                   const float* __restrict__ Wh,
                                                   const float* __restrict__ Wo,
                                                   const float* __restrict__ bi,
                                                   const float* __restrict__ bh,
                                                   const float* __restrict__ f_bonds,
                                                   const int* __restrict__ a2b,
                                                   unsigned short* __restrict__ Wi_t,
                                                   unsigned short* __restrict__ Wb_t,
                                                   unsigned short* __restrict__ Whm_t,
                                                   unsigned short* __restrict__ Woa_t,
                                                   unsigned short* __restrict__ Wom_t,
                                                   unsigned short* __restrict__ bondsum,
                                                   float* __restrict__ b_ih) {
    if (blockIdx.x < 256) {
        const int n = blockIdx.x;
        if (n == 0) b_ih[threadIdx.x] = bi[threadIdx.x] + bh[threadIdx.x];
        for (int k = threadIdx.x; k < KI; k += 256) {
            Wi_t[n * KI + k]  = f2bf(k < AF ? Wi[k * HID + n] : 0.f);
            Woa_t[n * KI + k] = f2bf(k < AF ? Wo[k * HID + n] : 0.f);
        }
        for (int k = threadIdx.x; k < KB; k += 256)
            Wb_t[n * KB + k] = f2bf(k < 14 ? Wh[(HID + k) * HID + n] : 0.f);
        for (int k = threadIdx.x; k < KP; k += 256) {
            Whm_t[n * KP + k] = f2bf(Wh[k * HID + n]);
            Wom_t[n * KP + k] = f2bf(Wo[(AF + k) * HID + n]);
        }
    } else {
        const int id   = (blockIdx.x - 256) * 256 + threadIdx.x;
        const int atom = id >> 4;
        const int c    = id & 15;
        float s = 0.f;
        if (c < 14) {
            const int* nb = &a2b[atom * NNB];
#pragma unroll
            for (int t = 0; t < NNB; ++t)
                s += f_bonds[(size_t)nb[t] * BT + (BT - 14) + c];
        }
        bondsum[atom * 32 + c]      = f2bf(s);
        bondsum[atom * 32 + 16 + c] = 0;
    }
}

// ---------------------------------------------------------------------------
// MFMA core (2 row-tiles of 16): C += A_lds[32 x K] @ W_t[256 x K]^T
// ---------------------------------------------------------------------------
template<int K, int LS>
__device__ __forceinline__ void mfma_core(const unsigned short* __restrict__ As,
                                          const unsigned short* __restrict__ Wt,
                                          f32x4 (&acc)[2][4], int wave, int lane) {
    const int lm = lane & 15, quad = lane >> 4;
    for (int ks = 0; ks < K; ks += 32) {
        short8 af[2], bf[4];
#pragma unroll
        for (int rt = 0; rt < 2; ++rt)
            af[rt] = *(const short8*)&As[(rt * 16 + lm) * LS + ks + quad * 8];
#pragma unroll
        for (int ct = 0; ct < 4; ++ct)
            bf[ct] = *(const short8*)&Wt[(size_t)(wave * 64 + ct * 16 + lm) * K + ks + quad * 8];
#pragma unroll
        for (int rt = 0; rt < 2; ++rt)
#pragma unroll
            for (int ct = 0; ct < 4; ++ct)
                acc[rt][ct] = __builtin_amdgcn_mfma_f32_16x16x32_bf16(af[rt], bf[ct], acc[rt][ct], 0, 0, 0);
    }
}

// Dual-B variant: two GEMMs sharing the same A fragments (half the ds_reads).
template<int K, int LS>
__device__ __forceinline__ void mfma_core2(const unsigned short* __restrict__ As,
                                           const unsigned short* __restrict__ WtA,
                                           const unsigned short* __restrict__ WtB,
                                           f32x4 (&accA)[2][4], f32x4 (&accB)[2][4],
                                           int wave, int lane) {
    const int lm = lane & 15, quad = lane >> 4;
    for (int ks = 0; ks < K; ks += 32) {
        short8 af[2], bfA[4], bfB[4];
#pragma unroll
        for (int rt = 0; rt < 2; ++rt)
            af[rt] = *(const short8*)&As[(rt * 16 + lm) * LS + ks + quad * 8];
#pragma unroll
        for (int ct = 0; ct < 4; ++ct) {
            size_t off = (size_t)(wave * 64 + ct * 16 + lm) * K + ks + quad * 8;
            bfA[ct] = *(const short8*)&WtA[off];
            bfB[ct] = *(const short8*)&WtB[off];
        }
#pragma unroll
        for (int rt = 0; rt < 2; ++rt)
#pragma unroll
            for (int ct = 0; ct < 4; ++ct) {
                accA[rt][ct] = __builtin_amdgcn_mfma_f32_16x16x32_bf16(af[rt], bfA[ct], accA[rt][ct], 0, 0, 0);
                accB[rt][ct] = __builtin_amdgcn_mfma_f32_16x16x32_bf16(af[rt], bfB[ct], accB[rt][ct], 0, 0, 0);
            }
    }
}

// C-layout acc -> bf16 tile in LDS (rows 0..31, stride LSP)
__device__ __forceinline__ void epi_to_lds(f32x4 (&acc)[2][4],
                                           const float* __restrict__ bias,
                                           bool relu_,
                                           unsigned short* __restrict__ E,
                                           int wave, int lane) {
    const int lm = lane & 15, quad = lane >> 4;
#pragma unroll
    for (int ct = 0; ct < 4; ++ct) {
        int col = wave * 64 + ct * 16 + lm;
        float bv = bias ? bias[col] : 0.f;
#pragma unroll
        for (int rt = 0; rt < 2; ++rt)
#pragma unroll
            for (int i = 0; i < 4; ++i) {
                float v = acc[rt][ct][i] + bv;
                if (relu_) v = fmaxf(v, 0.f);
                E[(rt * 16 + quad * 4 + i) * LSP + col] = f2bf(v);
            }
    }
}

// coalesced 16B row-major store of a 32x256 LDS tile
__device__ __forceinline__ void store_tile32(unsigned short* __restrict__ dst, int base,
                                             const unsigned short* __restrict__ E, int tid) {
#pragma unroll
    for (int k = 0; k < 4; ++k) {
        int j = k * 256 + tid;
        int r = j >> 5, g = j & 31;
        *(short8*)&dst[(size_t)(base + r) * HID + g * 8] = *(const short8*)&E[r * LSP + g * 8];
    }
}

// ---------------------------------------------------------------------------
// k_inp (32-row tiles), fused front-end with early-retired accumulators:
//   acc1 = atom@Wi, acc3 = atom@Wo_a (shared A-frags)
//   aw = acc3 + bo (stored first -> acc3 dead)
//   mT = relu(acc1+bi); acc2 = mT@Whm -> P0; acc1 += bs@Wb -> inp2
// Peak live accs: 64 AGPR (acc1+acc3, then acc1+acc2).
// ---------------------------------------------------------------------------
__global__ __launch_bounds__(256, 4) void k_inp(const float* __restrict__ atom,
                                                const unsigned short* __restrict__ bondsum,
                                                const unsigned short* __restrict__ Wi_t,
                                                const unsigned short* __restrict__ Wb_t,
                                                const unsigned short* __restrict__ Whm_t,
                                                const unsigned short* __restrict__ Woa_t,
                                                const float* __restrict__ bi,
                                                const float* __restrict__ b_ih,
                                                const float* __restrict__ bo,
                                                unsigned short* __restrict__ P0,
                                                unsigned short* __restrict__ inp2,
                                                unsigned short* __restrict__ aw) {
    __shared__ unsigned short atomT[32 * LSI];   // 10.5 KB, persistent
    __shared__ unsigned short work[32 * LSP];    // 16.5 KB, mT / epilogue tile
    __shared__ unsigned short bs[32 * LSB];      // 2.5 KB
    const int tid  = threadIdx.x;
    const int base = blockIdx.x * 32;

    for (int it = tid; it < 32 * KI; it += 256) {
        int r = it / KI, c = it - r * KI;
        atomT[r * LSI + c] = f2bf(c < AF ? atom[(size_t)(base + r) * AF + c] : 0.f);
    }
    if (tid < 128) {
        int r = tid >> 2, c = (tid & 3) * 8;
        *(short8*)&bs[r * LSB + c] = *(const short8*)&bondsum[(size_t)(base + r) * 32 + c];
    }
    __syncthreads();                                    // (1)

    const int lane = tid & 63, wave = tid >> 6;
    f32x4 acc1[2][4] = {}, acc3[2][4] = {};
    mfma_core2<KI, LSI>(atomT, Wi_t, Woa_t, acc1, acc3, wave, lane);

    epi_to_lds(acc3, bo, false, work, wave, lane);      // first use of work
    __syncthreads();                                    // (2)
    store_tile32(aw, base, work, tid);                  // acc3 retires
    __syncthreads();                                    // (3)

    epi_to_lds(acc1, bi, true, work, wave, lane);       // mT = relu(inp)
    __syncthreads();                                    // (4)

    f32x4 acc2[2][4] = {};
    mfma_core<KP, LSP>(work, Whm_t, acc2, wave, lane);  // P0 = m @ Whm
    mfma_core<KB, LSB>(bs, Wb_t, acc1, wave, lane);     // + bond part
    __syncthreads();                                    // (5) mT reads done

    epi_to_lds(acc2, nullptr, false, work, wave, lane);
    __syncthreads();                                    // (6)
    store_tile32(P0, base, work, tid);
    __syncthreads();                                    // (7)
    epi_to_lds(acc1, b_ih, false, work, wave, lane);
    __syncthreads();                                    // (8)
    store_tile32(inp2, base, work, tid);
}

// ---------------------------------------------------------------------------
// k_it (fused gather+proj, 32-row tiles):
//   m = relu(base_ + sum_t Pin[a2a[.,t]])  (LDS only)
//   Pout = m @ Wt
// unroll 1 keeps ~6 outstanding loads/thread -> low VGPR, high occupancy.
// ---------------------------------------------------------------------------
__global__ __launch_bounds__(256, 6) void k_it(const unsigned short* __restrict__ Pin,
                                               const unsigned short* __restrict__ base_,
                                               const int* __restrict__ a2a,
                                               const unsigned short* __restrict__ Wt,
                                               unsigned short* __restrict__ Pout) {
    __shared__ unsigned short mT[32 * LSP];
    __shared__ int nb_l[32 * NNB];
    const int tid  = threadIdx.x;
    const int base = blockIdx.x * 32;

    if (tid < 32 * NNB) nb_l[tid] = a2a[base * NNB + tid];
    __syncthreads();

#pragma unroll 1
    for (int k = 0; k < 4; ++k) {
        int j = k * 256 + tid;
        int r = j >> 5, g = j & 31;
        const int* nb = &nb_l[r * NNB];
        float s[8] = {};
#pragma unroll
        for (int t = 0; t < NNB; ++t) {
            short8 u = *(const short8*)&Pin[(size_t)nb[t] * HID + g * 8];
#pragma unroll
            for (int q = 0; q < 8; ++q) s[q] += bf2f((unsigned short)u[q]);
        }
        short8 b = *(const short8*)&base_[(size_t)(base + r) * HID + g * 8];
        short8 o;
#pragma unroll
        for (int q = 0; q < 8; ++q)
            o[q] = (short)f2bf(fmaxf(s[q] + bf2f((unsigned short)b[q]), 0.f));
        *(short8*)&mT[r * LSP + g * 8] = o;
    }
    __syncthreads();

    const int lane = tid & 63, wave = tid >> 6;
    f32x4 acc[2][4] = {};
    mfma_core<KP, LSP>(mT, Wt, acc, wave, lane);
    __syncthreads();
    epi_to_lds(acc, nullptr, false, mT, wave, lane);
    __syncthreads();
    store_tile32(Pout, base, mT, tid);
}

// ---------------------------------------------------------------------------
// k_gseg (fused final gather + segment mean): one block per molecule.
// 8 row-slots x 32 col-groups; short8 loads; LDS partial reduce.
// ---------------------------------------------------------------------------
__global__ __launch_bounds__(256, 6) void k_gseg(const unsigned short* __restrict__ P,
                                                 const unsigned short* __restrict__ aw,
                                                 const int* __restrict__ a2a,
                                                 const int* __restrict__ seg,
                                                 float* __restrict__ out) {
    const int m = blockIdx.x;
    __shared__ int lohi[2];
    __shared__ float red[8 * 256];   // 8 KB
    if (threadIdx.x == 0) {
        int lo = 0, hi = N_ATOMS;
        while (lo < hi) { int mid = (lo + hi) >> 1; if (seg[mid] < m) lo = mid + 1; else hi = mid; }
        lohi[0] = lo;
        int lo2 = lo, hi2 = N_ATOMS;
        while (lo2 < hi2) { int mid = (lo2 + hi2) >> 1; if (seg[mid] < m + 1) lo2 = mid + 1; else hi2 = mid; }
        lohi[1] = lo2;
    }
    __syncthreads();
    const int lo = lohi[0], hi = lohi[1];
    const int slot = threadIdx.x >> 5;    // 0..7 (row slot)
    const int cg   = threadIdx.x & 31;    // 0..31 (8-channel group)

    float s[8] = {};
#pragma unroll 1
    for (int i0 = lo; i0 < hi; i0 += 8) {
        int i = i0 + slot;
        if (i < hi) {
            const int* nb = &a2a[i * NNB];
            short8 a = *(const short8*)&aw[(size_t)i * HID + cg * 8];
            float v[8];
#pragma unroll
            for (int q = 0; q < 8; ++q) v[q] = bf2f((unsigned short)a[q]);
#pragma unroll
            for (int t = 0; t < NNB; ++t) {
                short8 u = *(const short8*)&P[(size_t)nb[t] * HID + cg * 8];
#pragma unroll
                for (int q = 0; q < 8; ++q) v[q] += bf2f((unsigned short)u[q]);
            }
#pragma unroll
            for (int q = 0; q < 8; ++q) s[q] += fmaxf(v[q], 0.f);
        }
    }
#pragma unroll
    for (int q = 0; q < 8; ++q) red[slot * 256 + cg * 8 + q] = s[q];
    __syncthreads();

    const int j = threadIdx.x;
    float tot = 0.f;
#pragma unroll
    for (int sl = 0; sl < 8; ++sl) tot += red[sl * 256 + j];
    const int cnt = hi - lo;
    out[m * HID + j] = (cnt > 0) ? (tot / (float)cnt) : 0.f;
}

// ---------------------------------------------------------------------------
extern "C" void kernel_launch(void* const* d_in, const int* in_sizes, int n_in,
                              void* d_out, int out_size, void* d_ws, size_t ws_size,
                              hipStream_t stream) {
    const float* atom    = (const float*)d_in[0];
    const float* f_bonds = (const float*)d_in[1];
    const int*   a2a     = (const int*)d_in[2];
    const int*   a2b     = (const int*)d_in[3];
    const int*   seg     = (const int*)d_in[4];
    const float* Wi      = (const float*)d_in[5];
    const float* bi      = (const float*)d_in[6];
    const float* Wh      = (const float*)d_in[7];
    const float* bh      = (const float*)d_in[8];
    const float* Wo      = (const float*)d_in[9];
    const float* bo      = (const float*)d_in[10];
    float* out = (float*)d_out;

    unsigned short* ws = (unsigned short*)d_ws;
    const size_t nh = (size_t)N_ATOMS * HID;
    unsigned short* Pa   = ws;               // 32 MB
    unsigned short* Pb   = Pa + nh;          // 32 MB
    unsigned short* inp2 = Pb + nh;          // 32 MB
    unsigned short* aw   = inp2 + nh;        // 32 MB
    unsigned short* bsum = aw + nh;          // 4 MB
    unsigned short* Wi_t  = bsum + (size_t)N_ATOMS * 32;
    unsigned short* Wb_t  = Wi_t + 256 * KI;
    unsigned short* Whm_t = Wb_t + 256 * KB;
    unsigned short* Woa_t = Whm_t + 256 * KP;
    unsigned short* Wom_t = Woa_t + 256 * KI;
    float*          b_ih  = (float*)(Wom_t + 256 * KP);

    dim3 blk(256);
    const int nb32 = N_ATOMS / 32;   // 2048

    k_prep_bond<<<256 + N_ATOMS * 16 / 256, blk, 0, stream>>>(
        Wi, Wh, Wo, bi, bh, f_bonds, a2b,
        Wi_t, Wb_t, Whm_t, Woa_t, Wom_t, bsum, b_ih);
    k_inp<<<nb32, blk, 0, stream>>>(atom, bsum, Wi_t, Wb_t, Whm_t, Woa_t,
                                    bi, b_ih, bo, Pa, inp2, aw);

    k_it<<<nb32, blk, 0, stream>>>(Pa, inp2, a2a, Whm_t, Pb);   // -> P1
    k_it<<<nb32, blk, 0, stream>>>(Pb, inp2, a2a, Wom_t, Pa);   // -> P2
    k_gseg<<<NM, blk, 0, stream>>>(Pa, aw, a2a, seg, out);
}